// Round 4
// baseline (145.073 us; speedup 1.0000x reference)
//
#include <hip/hip_runtime.h>

// InfoCNECauchy: loss = mean_r log(sum_{j!=r} sim[r,j]) - mean_r log(sim[r, r^4096])
// sim = t^2/(d2+t^2), d2 = ||f_r||^2 + ||f_c||^2 - 2<f_r,f_c>, t=0.07
//
// R9: R8 verbatim (BK=64, banded XCD map, XOR-swizzled LDS, 0 conflicts)
// with ONE change: 512 threads / 8 waves per 128^2 tile (wave owns 64x32)
// instead of 256/4. R8 post-mortem: occupancy 26% = 2 blocks/CU (148 unified
// regs/thread: 64 AGPR acc + 84 VGPR -> 2 waves/SIMD cliff at 128). All
// bandwidth & barrier-count theories falsified; per-pipe content arithmetic
// shows pipes ~85% idle -> latency-bound on resident-wave count. Halving
// per-thread acc (32 regs) + fragments (24) lands ~110 regs -> 4 waves/SIMD
// (__launch_bounds__(512,4)), 16 waves/CU: double the coverage pool.

#define N2 8192
#define DIM 512
#define NT 64 /* 8192/128 tiles per dim */
#define NTILES (NT * (NT + 1) / 2)
#define T2 0.0049f

typedef float floatx4 __attribute__((ext_vector_type(4)));
typedef __bf16 bf16x8 __attribute__((ext_vector_type(8)));
typedef __bf16 bf16x4 __attribute__((ext_vector_type(4)));

__device__ __forceinline__ void load_to_lds16(const void* g, void* l) {
  auto gp = (const __attribute__((address_space(1))) void*)(reinterpret_cast<uintptr_t>(g));
  auto lp = (__attribute__((address_space(3))) void*)(reinterpret_cast<uintptr_t>(l));
  __builtin_amdgcn_global_load_lds(gp, lp, 16, 0, 0);
}

// ---- prep: fp32 -> bf16 + row norms + zero rowsum ------------------------
__global__ __launch_bounds__(256) void prep_kernel(const float* __restrict__ f,
                                                   __bf16* __restrict__ fbf,
                                                   float* __restrict__ sq,
                                                   float* __restrict__ rowsum) {
  const int t = threadIdx.x;
  if (t < 2) rowsum[blockIdx.x * 2 + t] = 0.f;
  const int row = blockIdx.x * 2 + (t >> 7);
  const int ci = (t & 127) * 4;
  const float4 v = *(const float4*)(f + (size_t)row * DIM + ci);
  bf16x4 b;
  b[0] = (__bf16)v.x; b[1] = (__bf16)v.y; b[2] = (__bf16)v.z; b[3] = (__bf16)v.w;
  *(bf16x4*)(fbf + (size_t)row * DIM + ci) = b;
  float s = v.x * v.x + v.y * v.y + v.z * v.z + v.w * v.w;
#pragma unroll
  for (int off = 1; off < 64; off <<= 1) s += __shfl_xor(s, off, 64);
  __shared__ float red[4];
  if ((t & 63) == 0) red[t >> 6] = s;
  __syncthreads();
  if ((t & 127) == 0) sq[row] = red[t >> 6] + red[(t >> 6) + 1];
}

// ---- fused GEMM (upper tri, banded XCD order, BK=64, 8 waves) + epilogue --
__global__ __launch_bounds__(512, 4) void gemm_kernel(const __bf16* __restrict__ fbf,
                                                      const float* __restrict__ sq,
                                                      float* __restrict__ rowsum,
                                                      float* __restrict__ spart) {
  // two XOR-swizzled 8KB sub-regions (ks=0/1) per tensor
  __shared__ __bf16 aT[128 * 64];
  __shared__ __bf16 bT[128 * 64];

  // R5's banded tile decode (empirically best): XCD x owns row-bands
  // by in [4x,4x+4) and [60-4x,64-4x), bx-major, 260 tiles each.
  int by, bx;
  {
    const int x = blockIdx.x & 7;
    int kk = blockIdx.x >> 3;
    int band = x;
    const int n1 = 250 - 16 * x;
    if (kk >= n1) { kk -= n1; band = 15 - x; }
    const int by0 = band * 4;
    int bxx = by0;
    int cnt;
    while (kk >= (cnt = min(4, bxx - by0 + 1))) { kk -= cnt; ++bxx; }
    by = by0 + kk;
    bx = bxx;
  }
  const int brow = by * 128;
  const int bcol = bx * 128;
  const bool diag = (by == bx);

  const int t = threadIdx.x;
  const int lane = t & 63;
  const int w = t >> 6;               // 0..7
  const int wrow = (w >> 2) * 64;     // 0 or 64 (M half)
  const int wcol = (w & 3) * 32;      // 0,32,64,96 (N strip)
  const int q4 = lane >> 4;  // 0..3
  const int lc = lane & 15;  // 0..15

  floatx4 acc[4][2] = {};    // [mr][mc]: 64x32 per wave

  // staging lane -> (global row, 16B chunk) under XOR swizzle (per sub-region):
  // LDS slot (rp, u') holds global (row = rp*2 + (u>>2), chunk = u&3), u = u'^(rp&7)
  // 512 threads cover one 8KB region exactly (slot = t).
  const int rp = t >> 3;
  const int uu = (t & 7) ^ (rp & 7);
  const int grow = rp * 2 + (uu >> 2);  // 0..127
  const int gofs = (uu & 3) * 8;        // bf16 elements

  // fragment-read swizzle: u = (rr&1)*4+q4, u' = u ^ ((rr>>1)&7); rr = lc here.
  const int up = (((lc & 1) * 4) + q4) ^ (lc >> 1);
  const int rhalf = lc >> 1;

  for (int kt = 0; kt < DIM / 64; ++kt) {
    const int k0 = kt * 64;
#pragma unroll
    for (int ks = 0; ks < 2; ++ks) {
      load_to_lds16(fbf + (size_t)(brow + grow) * DIM + k0 + ks * 32 + gofs,
                    &aT[ks * 4096 + t * 8]);
      load_to_lds16(fbf + (size_t)(bcol + grow) * DIM + k0 + ks * 32 + gofs,
                    &bT[ks * 4096 + t * 8]);
    }
    __syncthreads();
#pragma unroll
    for (int ks = 0; ks < 2; ++ks) {
      bf16x8 af[4], bfr[2];
#pragma unroll
      for (int mr = 0; mr < 4; ++mr)
        af[mr] = *(const bf16x8*)&aT[ks * 4096 + ((wrow >> 1) + mr * 8 + rhalf) * 64 + up * 8];
#pragma unroll
      for (int mc = 0; mc < 2; ++mc)
        bfr[mc] = *(const bf16x8*)&bT[ks * 4096 + ((wcol >> 1) + mc * 8 + rhalf) * 64 + up * 8];
#pragma unroll
      for (int mr = 0; mr < 4; ++mr)
#pragma unroll
        for (int mc = 0; mc < 2; ++mc)
          acc[mr][mc] =
              __builtin_amdgcn_mfma_f32_16x16x32_bf16(af[mr], bfr[mc], acc[mr][mc], 0, 0, 0);
    }
    __syncthreads();
  }

  // Epilogue. C/D layout: col = lane&15, row = (lane>>4)*4 + reg.
  float sqc[2];
#pragma unroll
  for (int mc = 0; mc < 2; ++mc) sqc[mc] = sq[bcol + wcol + mc * 16 + lc];

  float cs[2] = {0.f, 0.f};  // column partial sums (off-diag tiles)

#pragma unroll
  for (int mr = 0; mr < 4; ++mr) {
#pragma unroll
    for (int reg = 0; reg < 4; ++reg) {
      const int r = brow + wrow + mr * 16 + q4 * 4 + reg;
      const float sr = sq[r];
      const int pc = r ^ (N2 / 2);
      float rs = 0.f;
#pragma unroll
      for (int mc = 0; mc < 2; ++mc) {
        const int c = bcol + wcol + mc * 16 + lc;
        const float g = acc[mr][mc][reg];
        const float d2 = fmaxf(sr + sqc[mc] - 2.f * g, 0.f);
        const float s = T2 * __builtin_amdgcn_rcpf(d2 + T2);
        if (c != r) rs += s;  // diagonal excluded exactly (diag tiles only)
        cs[mc] += s;          // unused on diag tiles
        if (c == pc) { spart[r] = s; spart[pc] = s; }  // off-diag only, 1 lane
      }
#pragma unroll
      for (int off = 1; off < 16; off <<= 1) rs += __shfl_xor(rs, off, 64);
      if (lc == 0) atomicAdd(&rowsum[r], rs);
    }
  }

  if (!diag) {
#pragma unroll
    for (int mc = 0; mc < 2; ++mc) {
      float v = cs[mc];
      v += __shfl_xor(v, 16, 64);
      v += __shfl_xor(v, 32, 64);
      if (lane < 16) atomicAdd(&rowsum[bcol + wcol + mc * 16 + lane], v);
    }
  }
}

// ---- final scalar reduction ---------------------------------------------
__global__ __launch_bounds__(256) void final_kernel(const float* __restrict__ rowsum,
                                                    const float* __restrict__ spart,
                                                    float* __restrict__ out) {
  const int t = threadIdx.x;
  float a = 0.f;
  for (int r = t; r < N2; r += 256) a += logf(rowsum[r]) - logf(spart[r]);
#pragma unroll
  for (int off = 1; off < 64; off <<= 1) a += __shfl_xor(a, off, 64);
  __shared__ float red[4];
  if ((t & 63) == 0) red[t >> 6] = a;
  __syncthreads();
  if (t == 0) out[0] = (red[0] + red[1] + red[2] + red[3]) * (1.0f / (float)N2);
}

extern "C" void kernel_launch(void* const* d_in, const int* in_sizes, int n_in,
                              void* d_out, int out_size, void* d_ws, size_t ws_size,
                              hipStream_t stream) {
  const float* features = (const float*)d_in[0];
  float* out = (float*)d_out;

  char* ws = (char*)d_ws;
  __bf16* fbf = (__bf16*)ws;                                     // 8 MB
  float* sq = (float*)(ws + (size_t)N2 * DIM * sizeof(__bf16));  // 32 KB
  float* rowsum = sq + N2;                                       // 32 KB
  float* spart = rowsum + N2;                                    // 32 KB

  prep_kernel<<<N2 / 2, 256, 0, stream>>>(features, fbf, sq, rowsum);
  gemm_kernel<<<NTILES, 512, 0, stream>>>(fbf, sq, rowsum, spart);
  final_kernel<<<1, 256, 0, stream>>>(rowsum, spart, out);
}